// Round 9
// baseline (453.745 us; speedup 1.0000x reference)
//
#include <hip/hip_runtime.h>

// RGCNConv: out_i = x_i @ W_root + bias + sum_r mean_{j in N_r(i)} x_j @ W_r
//
// R9 = R8 + cache-policy fixes (no structural change):
//   - aggregate: nontemporal store of mean (205 MB stream) -> xbf stays L3-hot
//   - reorder:   nontemporal loads of dst/et/src -> partitioned spack/cursor
//                stay resident in the owning XCD's L2 (kill 15x write amp)
//   - hist:      single pass (was 8 partitioned passes re-reading dst/et)

constexpr int D = 128;
constexpr int R = 8;

typedef __bf16 bf16x8 __attribute__((ext_vector_type(8)));
typedef float  f32x4  __attribute__((ext_vector_type(4)));
typedef unsigned short u16x8 __attribute__((ext_vector_type(8)));
typedef unsigned short u16x4 __attribute__((ext_vector_type(4)));

__device__ __forceinline__ unsigned short f2bf(float f) {
    unsigned u = __builtin_bit_cast(unsigned, f);
    u += 0x7FFFu + ((u >> 16) & 1u);          // round-to-nearest-even
    return (unsigned short)(u >> 16);
}

// ---- phase 0: x -> bf16 ----
__global__ __launch_bounds__(256)
void xbf_kernel(const float* __restrict__ x, unsigned short* __restrict__ xbf, int nquad) {
    int stride = gridDim.x * 256;
    for (int i = blockIdx.x * 256 + threadIdx.x; i < nquad; i += stride) {
        float4 v = ((const float4*)x)[i];
        u16x4 o;
        o[0] = f2bf(v.x); o[1] = f2bf(v.y); o[2] = f2bf(v.z); o[3] = f2bf(v.w);
        ((u16x4*)xbf)[i] = o;
    }
}

// ---- hist: single pass, NT reads ----
__global__ __launch_bounds__(256)
void hist_kernel(const int* __restrict__ dst, const int* __restrict__ et,
                 int* __restrict__ hist, int E) {
    int stride = gridDim.x * 256;
    for (int e = blockIdx.x * 256 + threadIdx.x; e < E; e += stride) {
        int d = __builtin_nontemporal_load(&dst[e]);
        int t = __builtin_nontemporal_load(&et[e]);
        atomicAdd(&hist[d * R + t], 1);
    }
}

__global__ __launch_bounds__(256)
void block_sums_kernel(const int* __restrict__ hs, int* __restrict__ bsum, int n) {
    __shared__ int sh[256];
    int i = blockIdx.x * 256 + threadIdx.x;
    sh[threadIdx.x] = (i < n) ? hs[i] : 0;
    __syncthreads();
    for (int off = 128; off > 0; off >>= 1) {
        if (threadIdx.x < off) sh[threadIdx.x] += sh[threadIdx.x + off];
        __syncthreads();
    }
    if (threadIdx.x == 0) bsum[blockIdx.x] = sh[0];
}

__global__ __launch_bounds__(64)
void scan_bsum_kernel(int* __restrict__ bsum, int nb) {
    int lane = threadIdx.x;
    int carry = 0;
    for (int base = 0; base < nb; base += 64) {
        int i = base + lane;
        int orig = (i < nb) ? bsum[i] : 0;
        int v = orig;
        #pragma unroll
        for (int off = 1; off < 64; off <<= 1) {
            int u = __shfl_up(v, off, 64);
            if (lane >= off) v += u;
        }
        int tot = __shfl(v, 63, 64);
        if (i < nb) bsum[i] = carry + (v - orig);
        carry += tot;
    }
}

__global__ __launch_bounds__(256)
void scan_block_kernel(int* __restrict__ hs, const int* __restrict__ bsum,
                       int* __restrict__ cursor, int n, int E) {
    __shared__ int sh[256];
    int tid = threadIdx.x;
    int i = blockIdx.x * 256 + tid;
    int v = (i < n) ? hs[i] : 0;
    sh[tid] = v;
    __syncthreads();
    for (int off = 1; off < 256; off <<= 1) {
        int u = (tid >= off) ? sh[tid - off] : 0;
        __syncthreads();
        sh[tid] += u;
        __syncthreads();
    }
    int st = bsum[blockIdx.x] + sh[tid] - v;
    if (i < n) { hs[i] = st; cursor[i] = st; }
    if (i == n) hs[n] = E;
}

// ---- reorder: XCD-partitioned, NT reads keep L2 for spack/cursor ----
__global__ __launch_bounds__(256)
void reorder_kernel(const int* __restrict__ src, const int* __restrict__ dst,
                    const int* __restrict__ et, int* __restrict__ cursor,
                    int* __restrict__ spack, int E) {
    int part   = blockIdx.x & 7;
    int stride = (gridDim.x >> 3) * 256;
    for (int e = (blockIdx.x >> 3) * 256 + threadIdx.x; e < E; e += stride) {
        int d = __builtin_nontemporal_load(&dst[e]);
        int t = __builtin_nontemporal_load(&et[e]);
        int seg = d * R + t;
        if (((seg >> 4) & 7) == part) {
            int s = __builtin_nontemporal_load(&src[e]);
            int pos = atomicAdd(&cursor[seg], 1);
            spack[pos] = s;
        }
    }
}

// ---- aggregate: mean_bf[seg][CW], NT store (protect xbf residency) ----
__global__ __launch_bounds__(256)
void aggregate_kernel(const unsigned short* __restrict__ xbf,
                      const int* __restrict__ spack,
                      const int* __restrict__ hstart,
                      unsigned short* __restrict__ mean,
                      int nseg, int tshift, int c0) {
    int idx = blockIdx.x * 256 + threadIdx.x;
    int seg = idx >> tshift;
    int c8  = idx & ((1 << tshift) - 1);
    if (seg >= nseg) return;
    int p0 = hstart[seg], p1 = hstart[seg + 1];
    int coff = c0 + c8 * 8;
    float a[8] = {};
    for (int p = p0; p < p1; ++p) {
        int s = spack[p];
        u16x8 v = *(const u16x8*)(xbf + ((size_t)s << 7) + coff);
        #pragma unroll
        for (int j = 0; j < 8; ++j)
            a[j] += __builtin_bit_cast(float, (unsigned)v[j] << 16);
    }
    float inv = (p1 > p0) ? 1.0f / (float)(p1 - p0) : 0.0f;
    u16x8 o;
    #pragma unroll
    for (int j = 0; j < 8; ++j) o[j] = f2bf(a[j] * inv);
    __builtin_nontemporal_store(o, (u16x8*)(mean + ((size_t)seg << (tshift + 3)) + c8 * 8));
}

// ---- WallTc[n][kk] bf16 for one pass ----
__global__ __launch_bounds__(256)
void wallt_kernel(const float* __restrict__ Wroot, const float* __restrict__ W,
                  unsigned short* __restrict__ WallTc, int KW, int CW, int c0, int first) {
    int idx = blockIdx.x * 256 + threadIdx.x;
    if (idx >= 128 * KW) return;
    int n = idx / KW, kk = idx % KW;
    float v;
    if (first && kk < 128) {
        v = Wroot[kk * 128 + n];
    } else {
        int lk = kk - (first ? 128 : 0);
        int r = lk / CW, cc = lk % CW;
        v = W[((size_t)r * 128 + c0 + cc) * 128 + n];
    }
    WallTc[idx] = f2bf(v);
}

// ---- MFMA GEMM: out[128-tile][128] (+)= [xbf | mean] @ WallTc ----
template<bool FIRST>
__global__ __launch_bounds__(256)
void mfma_gemm_kernel(const unsigned short* __restrict__ xbf,
                      const unsigned short* __restrict__ mean,
                      const unsigned short* __restrict__ WallTc,
                      const float* __restrict__ bias,
                      float* __restrict__ out,
                      int N, int NT, int KW, int MROW) {
    __shared__ unsigned short As[128][32];
    __shared__ unsigned short Bs[128][32];
    const int tid  = threadIdx.x;
    const int row0 = blockIdx.x * 128;
    const int lane = tid & 63;
    const int wid  = tid >> 6;
    const int wm   = wid >> 1;         // wave grid 2x2, each wave 64x64
    const int wn   = wid & 1;
    const int srow = tid >> 1;         // staging row 0..127
    const int sh16 = (tid & 1) * 16;   // staging k-offset (elems)

    f32x4 acc[4][4] = {};

    const int  node = row0 + srow;
    const bool nok  = node < N;

    for (int kt = 0; kt < NT; ++kt) {
        if (kt) __syncthreads();
        u16x8 a0, a1;
        #pragma unroll
        for (int j = 0; j < 8; ++j) { a0[j] = 0; a1[j] = 0; }
        if (FIRST && kt < 4) {
            if (nok) {
                const u16x8* xp = (const u16x8*)(xbf + ((size_t)node << 7) + kt * 32 + sh16);
                a0 = xp[0]; a1 = xp[1];
            }
        } else {
            if (nok) {
                const u16x8* mp = (const u16x8*)(mean + (size_t)node * MROW
                                                 + (kt - (FIRST ? 4 : 0)) * 32 + sh16);
                a0 = mp[0]; a1 = mp[1];
            }
        }
        const u16x8* wp = (const u16x8*)(WallTc + (size_t)srow * KW + kt * 32 + sh16);
        u16x8 b0 = wp[0], b1 = wp[1];

        *(u16x8*)&As[srow][sh16]     = a0;
        *(u16x8*)&As[srow][sh16 + 8] = a1;
        *(u16x8*)&Bs[srow][sh16]     = b0;
        *(u16x8*)&Bs[srow][sh16 + 8] = b1;
        __syncthreads();

        const int kg = (lane >> 4) * 8;
        const int rl = lane & 15;
        bf16x8 av[4], bv[4];
        #pragma unroll
        for (int f = 0; f < 4; ++f) {
            av[f] = __builtin_bit_cast(bf16x8, *(const u16x8*)&As[wm * 64 + f * 16 + rl][kg]);
            bv[f] = __builtin_bit_cast(bf16x8, *(const u16x8*)&Bs[wn * 64 + f * 16 + rl][kg]);
        }
        #pragma unroll
        for (int mf = 0; mf < 4; ++mf)
            #pragma unroll
            for (int nf = 0; nf < 4; ++nf)
                acc[mf][nf] = __builtin_amdgcn_mfma_f32_16x16x32_bf16(av[mf], bv[nf],
                                                                     acc[mf][nf], 0, 0, 0);
    }

    const int rl = lane & 15;
    const int rg = lane >> 4;
    #pragma unroll
    for (int nf = 0; nf < 4; ++nf) {
        int n = wn * 64 + nf * 16 + rl;
        float bb = FIRST ? bias[n] : 0.0f;
        #pragma unroll
        for (int mf = 0; mf < 4; ++mf) {
            #pragma unroll
            for (int i = 0; i < 4; ++i) {
                int nd = row0 + wm * 64 + mf * 16 + rg * 4 + i;
                if (nd < N) {
                    size_t o = (size_t)nd * 128 + n;
                    if (FIRST) out[o] = acc[mf][nf][i] + bb;
                    else       out[o] += acc[mf][nf][i];
                }
            }
        }
    }
}

extern "C" void kernel_launch(void* const* d_in, const int* in_sizes, int n_in,
                              void* d_out, int out_size, void* d_ws, size_t ws_size,
                              hipStream_t stream) {
    const float* x     = (const float*)d_in[0];
    const float* W     = (const float*)d_in[1];
    const float* Wroot = (const float*)d_in[2];
    const float* bias  = (const float*)d_in[3];
    const int*   ei    = (const int*)d_in[4];
    const int*   et    = (const int*)d_in[5];
    float*       out   = (float*)d_out;

    const int N = in_sizes[0] / D;
    const int E = in_sizes[5];
    const int* src = ei;
    const int* dst = ei + E;

    const int NSEG = N * R;
    const int NB   = (NSEG + 256) / 256;

    const size_t xbf_bytes    = (size_t)N * D * 2;
    const size_t walltc_bytes = (size_t)128 * 1152 * 2;
    const size_t fixed_bytes  = xbf_bytes + walltc_bytes +
                                ((size_t)(NSEG + 1) + NSEG + E + NB) * 4 + 256;

    // largest CW that fits: 128 -> single pass (no out-RMW), else 64/32
    int CW = 0, tshift = 0;
    const int cands[3]   = {128, 64, 32};
    const int tshifts[3] = {4, 3, 2};
    for (int i = 0; i < 3; ++i) {
        size_t need = (size_t)NSEG * cands[i] * 2 + fixed_bytes;
        if (need <= ws_size) { CW = cands[i]; tshift = tshifts[i]; break; }
    }
    if (CW == 0) return;

    char* p = (char*)d_ws;
    unsigned short* mean   = (unsigned short*)p;  p += (size_t)NSEG * CW * 2;
    unsigned short* xbf    = (unsigned short*)p;  p += xbf_bytes;
    unsigned short* WallTc = (unsigned short*)p;  p += walltc_bytes;
    int* hstart = (int*)p;  p += (size_t)(NSEG + 1) * 4;
    int* cursor = (int*)p;  p += (size_t)NSEG * 4;
    int* spack  = (int*)p;  p += (size_t)E * 4;
    int* bsum   = (int*)p;

    hipMemsetAsync(hstart, 0, (size_t)(NSEG + 1) * 4, stream);

    xbf_kernel<<<2048, 256, 0, stream>>>(x, xbf, N * D / 4);

    hist_kernel<<<1024, 256, 0, stream>>>(dst, et, hstart, E);
    block_sums_kernel<<<NB, 256, 0, stream>>>(hstart, bsum, NSEG);
    scan_bsum_kernel<<<1, 64, 0, stream>>>(bsum, NB);
    scan_block_kernel<<<NB, 256, 0, stream>>>(hstart, bsum, cursor, NSEG, E);
    reorder_kernel<<<8 * 80, 256, 0, stream>>>(src, dst, et, cursor, spack, E);

    const int gx  = (N + 127) / 128;
    const int nch = D / CW;
    for (int c = 0; c < nch; ++c) {
        int c0    = c * CW;
        int first = (c == 0);
        long long aggth = (long long)NSEG << tshift;
        aggregate_kernel<<<(int)((aggth + 255) / 256), 256, 0, stream>>>(
            xbf, spack, hstart, mean, NSEG, tshift, c0);
        int KW   = (first ? 128 : 0) + R * CW;
        int NT   = KW / 32;
        int MROW = R * CW;
        wallt_kernel<<<(128 * KW + 255) / 256, 256, 0, stream>>>(
            Wroot, W, WallTc, KW, CW, c0, first);
        if (first)
            mfma_gemm_kernel<true><<<gx, 256, 0, stream>>>(
                xbf, mean, WallTc, bias, out, N, NT, KW, MROW);
        else
            mfma_gemm_kernel<false><<<gx, 256, 0, stream>>>(
                xbf, mean, WallTc, bias, out, N, NT, KW, MROW);
    }
}

// Round 10
// 435.656 us; speedup vs baseline: 1.0415x; 1.0415x over previous
//
#include <hip/hip_runtime.h>

// RGCNConv: out_i = x_i @ W_root + bias + sum_r mean_{j in N_r(i)} x_j @ W_r
//
// R10: two-level multisplit sort (dense writes) + R8/R9's best pieces:
//   0. xbf = bf16(x)                       (25.6 MB, stays L3-hot for gathers)
//   1. bcount: exact per-bucket counts     (bucket = (seg>>7)&7, 8 buckets)
//   2. bucketA: tile multisplit, (seg,src) -> dense per-bucket runs (ebuf)
//   3. hist: bucketed read, XCD-local atomics -> hstart
//   4. scan -> start/cursor
//   5. bucketB: part p reads own bucket, scatters into L2-resident spack slice
//   6. aggregate: mean_bf[seg][CW] from xbf, fp32 accum, NT store
//   7. MFMA GEMM: out = [xbf | mean] @ WallT_bf + bias   (CW=128 single pass)
//   ebuf aliases the mean buffer (disjoint lifetimes) -> no extra ws.

constexpr int D = 128;
constexpr int R = 8;
constexpr int TILE = 2048;

typedef __bf16 bf16x8 __attribute__((ext_vector_type(8)));
typedef float  f32x4  __attribute__((ext_vector_type(4)));
typedef unsigned short u16x8 __attribute__((ext_vector_type(8)));
typedef unsigned short u16x4 __attribute__((ext_vector_type(4)));

__device__ __forceinline__ unsigned short f2bf(float f) {
    unsigned u = __builtin_bit_cast(unsigned, f);
    u += 0x7FFFu + ((u >> 16) & 1u);          // round-to-nearest-even
    return (unsigned short)(u >> 16);
}

// ---- phase 0: x -> bf16 ----
__global__ __launch_bounds__(256)
void xbf_kernel(const float* __restrict__ x, unsigned short* __restrict__ xbf, int nquad) {
    int stride = gridDim.x * 256;
    for (int i = blockIdx.x * 256 + threadIdx.x; i < nquad; i += stride) {
        float4 v = ((const float4*)x)[i];
        u16x4 o;
        o[0] = f2bf(v.x); o[1] = f2bf(v.y); o[2] = f2bf(v.z); o[3] = f2bf(v.w);
        ((u16x4*)xbf)[i] = o;
    }
}

// ---- exact bucket counts (meta: bcnt[0..7], bstart[8..15], gcur[16..23]) ----
__global__ __launch_bounds__(256)
void bcount_kernel(const int* __restrict__ dst, const int* __restrict__ et,
                   int* __restrict__ meta, int E) {
    __shared__ int cnt8[8];
    if (threadIdx.x < 8) cnt8[threadIdx.x] = 0;
    __syncthreads();
    int stride = gridDim.x * 256;
    for (int e = blockIdx.x * 256 + threadIdx.x; e < E; e += stride) {
        int seg = dst[e] * R + et[e];
        atomicAdd(&cnt8[(seg >> 7) & 7], 1);
    }
    __syncthreads();
    if (threadIdx.x < 8) atomicAdd(&meta[threadIdx.x], cnt8[threadIdx.x]);
}

__global__ void bscan_kernel(int* __restrict__ meta) {
    if (threadIdx.x == 0) {
        int cum = 0;
        for (int p = 0; p < 8; ++p) {
            meta[8 + p]  = cum;   // bstart
            meta[16 + p] = cum;   // gcur
            cum += meta[p];
        }
    }
}

// ---- phase A: tile multisplit into dense per-bucket runs ----
__global__ __launch_bounds__(256)
void bucketA_kernel(const int* __restrict__ src, const int* __restrict__ dst,
                    const int* __restrict__ et, int* __restrict__ ebuf_seg,
                    int* __restrict__ ebuf_src, int* __restrict__ meta, int E) {
    __shared__ int cntw[4][8];
    __shared__ int basew[4][8];
    const int tid = threadIdx.x;
    const int w   = tid >> 6;
    for (int t0 = blockIdx.x * TILE; t0 < E; t0 += gridDim.x * TILE) {
        if (tid < 32) cntw[tid >> 3][tid & 7] = 0;
        __syncthreads();
        int seg[8], sr[8], pt[8];
        bool ok[8];
        #pragma unroll
        for (int j = 0; j < 8; ++j) {
            int e = t0 + j * 256 + tid;
            ok[j] = e < E;
            if (ok[j]) {
                seg[j] = dst[e] * R + et[e];
                sr[j]  = src[e];
                pt[j]  = (seg[j] >> 7) & 7;
                atomicAdd(&cntw[w][pt[j]], 1);
            }
        }
        __syncthreads();
        if (tid < 8) {
            int p = tid;
            int tot = cntw[0][p] + cntw[1][p] + cntw[2][p] + cntw[3][p];
            int b = atomicAdd(&meta[16 + p], tot);
            basew[0][p] = b;               b += cntw[0][p];
            basew[1][p] = b;               b += cntw[1][p];
            basew[2][p] = b;               b += cntw[2][p];
            basew[3][p] = b;
            cntw[0][p] = 0; cntw[1][p] = 0; cntw[2][p] = 0; cntw[3][p] = 0;
        }
        __syncthreads();
        #pragma unroll
        for (int j = 0; j < 8; ++j) {
            if (ok[j]) {
                int r   = atomicAdd(&cntw[w][pt[j]], 1);
                int pos = basew[w][pt[j]] + r;
                ebuf_seg[pos] = seg[j];
                ebuf_src[pos] = sr[j];
            }
        }
        __syncthreads();
    }
}

// ---- hist from bucketed segs: part p reads own bucket, XCD-local atomics ----
__global__ __launch_bounds__(256)
void hist_kernel(const int* __restrict__ ebuf_seg, const int* __restrict__ meta,
                 int* __restrict__ hist) {
    int part = blockIdx.x & 7;
    int nb   = gridDim.x >> 3;
    int lo   = meta[8 + part];
    int n    = meta[part];
    for (int i = (blockIdx.x >> 3) * 256 + threadIdx.x; i < n; i += nb * 256)
        atomicAdd(&hist[ebuf_seg[lo + i]], 1);
}

__global__ __launch_bounds__(256)
void block_sums_kernel(const int* __restrict__ hs, int* __restrict__ bsum, int n) {
    __shared__ int sh[256];
    int i = blockIdx.x * 256 + threadIdx.x;
    sh[threadIdx.x] = (i < n) ? hs[i] : 0;
    __syncthreads();
    for (int off = 128; off > 0; off >>= 1) {
        if (threadIdx.x < off) sh[threadIdx.x] += sh[threadIdx.x + off];
        __syncthreads();
    }
    if (threadIdx.x == 0) bsum[blockIdx.x] = sh[0];
}

__global__ __launch_bounds__(64)
void scan_bsum_kernel(int* __restrict__ bsum, int nb) {
    int lane = threadIdx.x;
    int carry = 0;
    for (int base = 0; base < nb; base += 64) {
        int i = base + lane;
        int orig = (i < nb) ? bsum[i] : 0;
        int v = orig;
        #pragma unroll
        for (int off = 1; off < 64; off <<= 1) {
            int u = __shfl_up(v, off, 64);
            if (lane >= off) v += u;
        }
        int tot = __shfl(v, 63, 64);
        if (i < nb) bsum[i] = carry + (v - orig);
        carry += tot;
    }
}

__global__ __launch_bounds__(256)
void scan_block_kernel(int* __restrict__ hs, const int* __restrict__ bsum,
                       int* __restrict__ cursor, int n, int E) {
    __shared__ int sh[256];
    int tid = threadIdx.x;
    int i = blockIdx.x * 256 + tid;
    int v = (i < n) ? hs[i] : 0;
    sh[tid] = v;
    __syncthreads();
    for (int off = 1; off < 256; off <<= 1) {
        int u = (tid >= off) ? sh[tid - off] : 0;
        __syncthreads();
        sh[tid] += u;
        __syncthreads();
    }
    int st = bsum[blockIdx.x] + sh[tid] - v;
    if (i < n) { hs[i] = st; cursor[i] = st; }
    if (i == n) hs[n] = E;
}

// ---- phase B: part p scatters own bucket into L2-resident spack slice ----
__global__ __launch_bounds__(256)
void bucketB_kernel(const int* __restrict__ ebuf_seg, const int* __restrict__ ebuf_src,
                    const int* __restrict__ meta, int* __restrict__ cursor,
                    int* __restrict__ spack) {
    int part = blockIdx.x & 7;
    int nb   = gridDim.x >> 3;
    int lo   = meta[8 + part];
    int n    = meta[part];
    for (int i = (blockIdx.x >> 3) * 256 + threadIdx.x; i < n; i += nb * 256) {
        int seg = ebuf_seg[lo + i];
        int s   = ebuf_src[lo + i];
        int pos = atomicAdd(&cursor[seg], 1);
        spack[pos] = s;
    }
}

// ---- aggregate: mean_bf[seg][CW], fp32 accum, NT store ----
__global__ __launch_bounds__(256)
void aggregate_kernel(const unsigned short* __restrict__ xbf,
                      const int* __restrict__ spack,
                      const int* __restrict__ hstart,
                      unsigned short* __restrict__ mean,
                      int nseg, int tshift, int c0) {
    int idx = blockIdx.x * 256 + threadIdx.x;
    int seg = idx >> tshift;
    int c8  = idx & ((1 << tshift) - 1);
    if (seg >= nseg) return;
    int p0 = hstart[seg], p1 = hstart[seg + 1];
    int coff = c0 + c8 * 8;
    float a[8] = {};
    for (int p = p0; p < p1; ++p) {
        int s = spack[p];
        u16x8 v = *(const u16x8*)(xbf + ((size_t)s << 7) + coff);
        #pragma unroll
        for (int j = 0; j < 8; ++j)
            a[j] += __builtin_bit_cast(float, (unsigned)v[j] << 16);
    }
    float inv = (p1 > p0) ? 1.0f / (float)(p1 - p0) : 0.0f;
    u16x8 o;
    #pragma unroll
    for (int j = 0; j < 8; ++j) o[j] = f2bf(a[j] * inv);
    __builtin_nontemporal_store(o, (u16x8*)(mean + ((size_t)seg << (tshift + 3)) + c8 * 8));
}

// ---- WallTc[n][kk] bf16 for one pass ----
__global__ __launch_bounds__(256)
void wallt_kernel(const float* __restrict__ Wroot, const float* __restrict__ W,
                  unsigned short* __restrict__ WallTc, int KW, int CW, int c0, int first) {
    int idx = blockIdx.x * 256 + threadIdx.x;
    if (idx >= 128 * KW) return;
    int n = idx / KW, kk = idx % KW;
    float v;
    if (first && kk < 128) {
        v = Wroot[kk * 128 + n];
    } else {
        int lk = kk - (first ? 128 : 0);
        int r = lk / CW, cc = lk % CW;
        v = W[((size_t)r * 128 + c0 + cc) * 128 + n];
    }
    WallTc[idx] = f2bf(v);
}

// ---- MFMA GEMM: out[128-tile][128] (+)= [xbf | mean] @ WallTc ----
template<bool FIRST>
__global__ __launch_bounds__(256)
void mfma_gemm_kernel(const unsigned short* __restrict__ xbf,
                      const unsigned short* __restrict__ mean,
                      const unsigned short* __restrict__ WallTc,
                      const float* __restrict__ bias,
                      float* __restrict__ out,
                      int N, int NT, int KW, int MROW) {
    __shared__ unsigned short As[128][32];
    __shared__ unsigned short Bs[128][32];
    const int tid  = threadIdx.x;
    const int row0 = blockIdx.x * 128;
    const int lane = tid & 63;
    const int wid  = tid >> 6;
    const int wm   = wid >> 1;
    const int wn   = wid & 1;
    const int srow = tid >> 1;
    const int sh16 = (tid & 1) * 16;

    f32x4 acc[4][4] = {};

    const int  node = row0 + srow;
    const bool nok  = node < N;

    for (int kt = 0; kt < NT; ++kt) {
        if (kt) __syncthreads();
        u16x8 a0, a1;
        #pragma unroll
        for (int j = 0; j < 8; ++j) { a0[j] = 0; a1[j] = 0; }
        if (FIRST && kt < 4) {
            if (nok) {
                const u16x8* xp = (const u16x8*)(xbf + ((size_t)node << 7) + kt * 32 + sh16);
                a0 = xp[0]; a1 = xp[1];
            }
        } else {
            if (nok) {
                const u16x8* mp = (const u16x8*)(mean + (size_t)node * MROW
                                                 + (kt - (FIRST ? 4 : 0)) * 32 + sh16);
                a0 = mp[0]; a1 = mp[1];
            }
        }
        const u16x8* wp = (const u16x8*)(WallTc + (size_t)srow * KW + kt * 32 + sh16);
        u16x8 b0 = wp[0], b1 = wp[1];

        *(u16x8*)&As[srow][sh16]     = a0;
        *(u16x8*)&As[srow][sh16 + 8] = a1;
        *(u16x8*)&Bs[srow][sh16]     = b0;
        *(u16x8*)&Bs[srow][sh16 + 8] = b1;
        __syncthreads();

        const int kg = (lane >> 4) * 8;
        const int rl = lane & 15;
        bf16x8 av[4], bv[4];
        #pragma unroll
        for (int f = 0; f < 4; ++f) {
            av[f] = __builtin_bit_cast(bf16x8, *(const u16x8*)&As[wm * 64 + f * 16 + rl][kg]);
            bv[f] = __builtin_bit_cast(bf16x8, *(const u16x8*)&Bs[wn * 64 + f * 16 + rl][kg]);
        }
        #pragma unroll
        for (int mf = 0; mf < 4; ++mf)
            #pragma unroll
            for (int nf = 0; nf < 4; ++nf)
                acc[mf][nf] = __builtin_amdgcn_mfma_f32_16x16x32_bf16(av[mf], bv[nf],
                                                                     acc[mf][nf], 0, 0, 0);
    }

    const int rl = lane & 15;
    const int rg = lane >> 4;
    #pragma unroll
    for (int nf = 0; nf < 4; ++nf) {
        int n = wn * 64 + nf * 16 + rl;
        float bb = FIRST ? bias[n] : 0.0f;
        #pragma unroll
        for (int mf = 0; mf < 4; ++mf) {
            #pragma unroll
            for (int i = 0; i < 4; ++i) {
                int nd = row0 + wm * 64 + mf * 16 + rg * 4 + i;
                if (nd < N) {
                    size_t o = (size_t)nd * 128 + n;
                    if (FIRST) out[o] = acc[mf][nf][i] + bb;
                    else       out[o] += acc[mf][nf][i];
                }
            }
        }
    }
}

extern "C" void kernel_launch(void* const* d_in, const int* in_sizes, int n_in,
                              void* d_out, int out_size, void* d_ws, size_t ws_size,
                              hipStream_t stream) {
    const float* x     = (const float*)d_in[0];
    const float* W     = (const float*)d_in[1];
    const float* Wroot = (const float*)d_in[2];
    const float* bias  = (const float*)d_in[3];
    const int*   ei    = (const int*)d_in[4];
    const int*   et    = (const int*)d_in[5];
    float*       out   = (float*)d_out;

    const int N = in_sizes[0] / D;
    const int E = in_sizes[5];
    const int* src = ei;
    const int* dst = ei + E;

    const int NSEG = N * R;
    const int NB   = (NSEG + 256) / 256;

    const size_t xbf_bytes    = (size_t)N * D * 2;
    const size_t walltc_bytes = (size_t)128 * 1152 * 2;
    const size_t fixed_bytes  = xbf_bytes + walltc_bytes +
                                ((size_t)(NSEG + 1) + NSEG + E + NB + 32) * 4 + 256;

    // largest CW that fits (mean buffer also hosts ebuf early; CW>=8 covers it)
    int CW = 0, tshift = 0;
    const int cands[3]   = {128, 64, 32};
    const int tshifts[3] = {4, 3, 2};
    for (int i = 0; i < 3; ++i) {
        size_t need = (size_t)NSEG * cands[i] * 2 + fixed_bytes;
        if (need <= ws_size) { CW = cands[i]; tshift = tshifts[i]; break; }
    }
    if (CW == 0) return;

    char* p = (char*)d_ws;
    unsigned short* mean   = (unsigned short*)p;  p += (size_t)NSEG * CW * 2;
    unsigned short* xbf    = (unsigned short*)p;  p += xbf_bytes;
    unsigned short* WallTc = (unsigned short*)p;  p += walltc_bytes;
    int* hstart = (int*)p;  p += (size_t)(NSEG + 1) * 4;
    int* cursor = (int*)p;  p += (size_t)NSEG * 4;
    int* spack  = (int*)p;  p += (size_t)E * 4;
    int* bsum   = (int*)p;  p += (size_t)NB * 4;
    int* meta   = (int*)p;                        // bcnt[8], bstart[8], gcur[8]

    // ebuf aliases mean (ebuf dead before aggregate writes mean)
    int* ebuf_seg = (int*)mean;
    int* ebuf_src = ebuf_seg + E;

    hipMemsetAsync(hstart, 0, (size_t)(NSEG + 1) * 4, stream);
    hipMemsetAsync(meta, 0, 32 * 4, stream);

    xbf_kernel<<<2048, 256, 0, stream>>>(x, xbf, N * D / 4);

    bcount_kernel<<<1024, 256, 0, stream>>>(dst, et, meta, E);
    bscan_kernel<<<1, 64, 0, stream>>>(meta);
    bucketA_kernel<<<(E + TILE - 1) / TILE, 256, 0, stream>>>(
        src, dst, et, ebuf_seg, ebuf_src, meta, E);
    hist_kernel<<<768, 256, 0, stream>>>(ebuf_seg, meta, hstart);
    block_sums_kernel<<<NB, 256, 0, stream>>>(hstart, bsum, NSEG);
    scan_bsum_kernel<<<1, 64, 0, stream>>>(bsum, NB);
    scan_block_kernel<<<NB, 256, 0, stream>>>(hstart, bsum, cursor, NSEG, E);
    bucketB_kernel<<<768, 256, 0, stream>>>(ebuf_seg, ebuf_src, meta, cursor, spack);

    const int gx  = (N + 127) / 128;
    const int nch = D / CW;
    for (int c = 0; c < nch; ++c) {
        int c0    = c * CW;
        int first = (c == 0);
        long long aggth = (long long)NSEG << tshift;
        aggregate_kernel<<<(int)((aggth + 255) / 256), 256, 0, stream>>>(
            xbf, spack, hstart, mean, NSEG, tshift, c0);
        int KW   = (first ? 128 : 0) + R * CW;
        int NT   = KW / 32;
        int MROW = R * CW;
        wallt_kernel<<<(128 * KW + 255) / 256, 256, 0, stream>>>(
            Wroot, W, WallTc, KW, CW, c0, first);
        if (first)
            mfma_gemm_kernel<true><<<gx, 256, 0, stream>>>(
                xbf, mean, WallTc, bias, out, N, NT, KW, MROW);
        else
            mfma_gemm_kernel<false><<<gx, 256, 0, stream>>>(
                xbf, mean, WallTc, bias, out, N, NT, KW, MROW);
    }
}